// Round 6
// baseline (95.469 us; speedup 1.0000x reference)
//
#include <hip/hip_runtime.h>

// Problem constants
#define HH 256
#define WW 256
#define BB 4
#define CC 3
#define HW 65536          // H*W
#define NM 24             // 2*B*C masks (0..11 lab, 12..23 pred)
#define NBLK 1024
#define BIGF 1e9f
#define LIMITF 331776.0f  // 576*576
#define EPSF 1e-5f

// Ledger (dur_us): R0 4-launch 80.8 | R2 fused 90.6 | R3 2-launch 85.0 |
// R4 3-launch 84.1 | R5 4-launch + bitmap d1 74.7. Structure: 41us harness
// fill + ~10us fixed graph overhead + ~23us kernels/transitions. Kernels are
// latency/ramp-bound (total traffic ~16MB = 2.5us at HBM); every in-kernel
// sync alternative measured worse than plain boundaries. R15: tail shaving -
// (1) blkmax becomes a per-mask global atomicMax on float-as-int bits (valid
// order for non-negative floats; max commutes -> bit-identical), removing
// colpass's block-level reduction and k_final's 768-load prologue; (2) acc
// init from registers (d1 just computed by the same thread), not LDS; (3)
// per-wave atomic (4/block) instead of LDS wmax stage. Slots zeroed by
// rowpass block 0 (boundary-ordered; correct under any re-poison semantics).

// ---------------------------------------------------------------------------
// Pass 1: per-(batch,row) zero-pixel bitmaps for all 6 masks + per-pixel
// code byte (lab | argmax<<2). grid: 4*256 blocks, 256 threads (col).
// bits layout: [m][row][4] u64 --- bit k of word w = column w*64+k.
// Block 0 also zeroes the 24 blkmax atomic slots (read only after boundary).
// ---------------------------------------------------------------------------
__global__ __launch_bounds__(256) void k_rowpass(const float* __restrict__ pred,
                                                 const int* __restrict__ lab,
                                                 unsigned long long* __restrict__ bits,
                                                 unsigned char* __restrict__ codes,
                                                 int* __restrict__ bmax) {
    int blk = blockIdx.x;
    int b = blk >> 8;
    int i = blk & 255;
    int j = threadIdx.x;

    if (blk == 0 && threadIdx.x < NM) bmax[threadIdx.x] = 0;   // 0.0f bits

    int lv = lab[(b << 16) + (i << 8) + j];
    const float* pb = pred + (((size_t)(b * 3)) << 16) + (i << 8) + j;
    float p0 = pb[0];
    float p1 = pb[(size_t)1 << 16];
    float p2 = pb[(size_t)2 << 16];
    int am = 0; float v = p0;
    if (p1 > v) { am = 1; v = p1; }
    if (p2 > v) { am = 2; }

    codes[(b << 16) + (i << 8) + j] = (unsigned char)(lv | (am << 2));

    __shared__ unsigned long long zm[6][4];
    int w = threadIdx.x >> 6;
    #pragma unroll
    for (int c = 0; c < 3; ++c) {
        unsigned long long zl = __ballot(lv != c);
        unsigned long long zp = __ballot(am != c);
        if ((threadIdx.x & 63) == 0) { zm[c][w] = zl; zm[3 + c][w] = zp; }
    }
    __syncthreads();

    // 24 u64 stores: thread t -> mask t>>2, word t&3 (32B contiguous/mask).
    if (threadIdx.x < 24) {
        int t = threadIdx.x >> 2;
        int w2 = threadIdx.x & 3;
        int c = (t < 3) ? t : (t - 3);
        int m = ((t < 3) ? 0 : 12) + b * 3 + c;
        bits[(((size_t)m) << 10) + (i << 2) + w2] = zm[t][w2];
    }
}

// ---------------------------------------------------------------------------
// Pass 2: recompute d1 from the mask bitmap (8KB in LDS), then column
// min-plus d[i,j]=min_k d1[k,j]+(i-k)^2 with the proven wave-uniform exact
// window (fast path Rmax<=32: guards make dk^2 a wave-scalar add,
// bit-identical; slow path: clamped, exact). One block owns 8 FULL columns.
// Per-mask max published via atomicMax on float bits (non-negative -> int
// ordering == float ordering; max is order-independent -> bit-exact).
// grid: 24*32 blocks, 256 threads.
// ---------------------------------------------------------------------------
__global__ __launch_bounds__(256) void k_colpass(const unsigned long long* __restrict__ bits,
                                                 float* __restrict__ dbuf,
                                                 int* __restrict__ bmax) {
    int blk = blockIdx.x;
    int m = blk >> 5;
    int j0 = (blk & 31) << 3;
    __shared__ float tile[320 * 9];            // rows 0..319 = k -32..287, stride 9
    __shared__ unsigned long long zb[256][4];  // row bitmaps, 8 KB
    float* base = dbuf + (((size_t)m) << 16);

    {   // stage bitmaps (1024 u64, 4/thread, coalesced) + guard rows = BIG
        const unsigned long long* bm = bits + (((size_t)m) << 10);
        int t = threadIdx.x;
        #pragma unroll
        for (int k = 0; k < 4; ++k) {
            int idx = t + (k << 8);
            zb[idx >> 2][idx & 3] = bm[idx];
        }
        int gr = t >> 3, gc = t & 7;
        tile[gr * 9 + gc] = BIGF;              // k = -32..-1
        tile[(288 + gr) * 9 + gc] = BIGF;      // k = 256..287
    }
    __syncthreads();

    int jj = threadIdx.x & 7;
    int ib = threadIdx.x >> 3;   // 0..31
    int j = j0 + jj;             // this thread's column

    // d1 for own 8 rows from the bitmap --- EXACT rowpass logic, relocated.
    // Kept in registers for the k=i accumulator init (skips 8 LDS reads).
    float d1v[8];
    #pragma unroll
    for (int r = 0; r < 8; ++r) {
        int row = ib + (r << 5);
        int bestd = 512;  // sentinel > any possible distance (<=255)
        #pragma unroll
        for (int w2 = 0; w2 < 4; ++w2) {
            unsigned long long z = zb[row][w2];
            int basew = w2 << 6;
            int rel = j - basew;
            unsigned long long mle;   // bits at positions <= rel
            if (rel >= 63)      mle = ~0ULL;
            else if (rel < 0)   mle = 0ULL;
            else                mle = (2ULL << rel) - 1ULL;
            unsigned long long zlo = z & mle;
            if (zlo) {
                int p = basew + 63 - __clzll(zlo);
                int d = j - p;
                if (d < bestd) bestd = d;
            }
            unsigned long long zr = z & ~mle;
            if (zr) {
                int p = basew + __ffsll(zr) - 1;
                int d = p - j;
                if (d < bestd) bestd = d;
            }
        }
        float d1 = (bestd >= 512) ? BIGF : (float)(bestd * bestd);
        d1v[r] = d1;
        tile[(row + 32) * 9 + jj] = d1;
    }
    __syncthreads();

    float acc[8];
    float dmax = 0.0f;
    #pragma unroll
    for (int r = 0; r < 8; ++r) {
        acc[r] = d1v[r];                        // k=i candidate (register)
        dmax = fmaxf(dmax, acc[r]);
    }
    #pragma unroll
    for (int off = 32; off; off >>= 1)
        dmax = fmaxf(dmax, __shfl_xor(dmax, off, 64));
    int Rmax = (int)sqrtf(dmax) + 1;
    if (Rmax > 255) Rmax = 255;

    if (Rmax <= 32) {
        // Fast path: guards cover k=i+o fully; dk^2 = o^2 wave-scalar.
        for (int o = -Rmax; o <= Rmax; ++o) {
            float o2 = (float)(o * o);
            #pragma unroll
            for (int r = 0; r < 8; ++r)
                acc[r] = fminf(acc[r], o2 + tile[(ib + (r << 5) + 32 + o) * 9 + jj]);
        }
    } else {
        // Slow path (BIG rows in wave): clamped candidates, exact full logic.
        for (int o = -Rmax; o <= Rmax; ++o) {
            #pragma unroll
            for (int r = 0; r < 8; ++r) {
                int i = ib + (r << 5);
                int k = i + o;
                k = (k < 0) ? 0 : ((k > 255) ? 255 : k);
                float dk = (float)(k - i);
                acc[r] = fminf(acc[r], fmaf(dk, dk, tile[(k + 32) * 9 + jj]));
            }
        }
    }

    float lmax = 0.0f;
    #pragma unroll
    for (int r = 0; r < 8; ++r) {
        int i = ib + (r << 5);
        base[(i << 8) + j0 + jj] = acc[r];
        lmax = fmaxf(lmax, acc[r]);
    }

    #pragma unroll
    for (int off = 32; off; off >>= 1)
        lmax = fmaxf(lmax, __shfl_down(lmax, off, 64));
    // Per-wave publish: distances are >= 0, so float order == int-bit order.
    if ((threadIdx.x & 63) == 0)
        atomicMax(&bmax[m], __float_as_int(lmax));
}

// ---------------------------------------------------------------------------
// Pass 3: per-pixel cosine sim -> per-BLOCK partials. Prologue is now 24
// direct loads of the per-mask maxima. grid: 1024 blocks x 256.
// ---------------------------------------------------------------------------
__global__ __launch_bounds__(256) void k_final(const unsigned char* __restrict__ codes,
                                               const float* __restrict__ dbuf,
                                               const int* __restrict__ bmax,
                                               float* __restrict__ psum,
                                               int* __restrict__ pfg) {
    __shared__ float inv[NM];
    if (threadIdx.x < NM) {
        float v = __int_as_float(bmax[threadIdx.x]);
        inv[threadIdx.x] = 1.0f / (fminf(sqrtf(v), LIMITF) + EPSF);
    }
    __syncthreads();

    int b = blockIdx.x >> 8;                         // uniform per block
    int pix = ((blockIdx.x & 255) << 8) + threadIdx.x;

    int code = codes[(b << 16) + pix];
    int lv = code & 3;
    int am = code >> 2;

    float slab = 0.0f, spred = 0.0f;
    #pragma unroll
    for (int c = 0; c < 3; ++c) {
        int ml = b * 3 + c;
        float dl = dbuf[(((size_t)ml) << 16) + pix];
        slab += sqrtf(dl) * inv[ml];
        float dp = dbuf[(((size_t)(ml + 12)) << 16) + pix];
        spred += sqrtf(dp) * inv[ml + 12];
    }

    float dot = spred * slab + ((am == lv) ? 1.0f : 0.0f);
    float na = sqrtf(spred * spred + 1.0f);
    float nb = sqrtf(slab * slab + 1.0f);
    float sim = dot / (fmaxf(na, 1e-8f) * fmaxf(nb, 1e-8f));

    unsigned long long fg = __ballot(lv > 0);

    #pragma unroll
    for (int off = 32; off; off >>= 1)
        sim += __shfl_down(sim, off, 64);
    __shared__ float wsum[4];
    __shared__ int wfg[4];
    if ((threadIdx.x & 63) == 0) {
        wsum[threadIdx.x >> 6] = sim;
        wfg[threadIdx.x >> 6] = (fg != 0ULL) ? 1 : 0;
    }
    __syncthreads();
    if (threadIdx.x == 0) {
        psum[blockIdx.x] = wsum[0] + wsum[1] + wsum[2] + wsum[3];
        pfg[blockIdx.x] = wfg[0] | wfg[1] | wfg[2] | wfg[3];
    }
}

// ---------------------------------------------------------------------------
// Reduce 1024 block partials -> loss (byte-identical to R0).
// ---------------------------------------------------------------------------
__global__ __launch_bounds__(256) void k_finalize(const float* __restrict__ psum,
                                                  const int* __restrict__ pfg,
                                                  float* __restrict__ out) {
    int t = threadIdx.x;
    int b = t >> 6, l = t & 63;
    int base = (b << 8) + l;
    float s = psum[base] + psum[base + 64] + psum[base + 128] + psum[base + 192];
    int f = pfg[base] | pfg[base + 64] | pfg[base + 128] | pfg[base + 192];
    #pragma unroll
    for (int off = 32; off; off >>= 1) {
        s += __shfl_down(s, off, 64);
        f |= __shfl_down(f, off, 64);
    }
    __shared__ float bsum[4];
    __shared__ int bfg[4];
    if (l == 0) { bsum[b] = s; bfg[b] = f; }
    __syncthreads();
    if (t == 0) {
        float loss = 0.0f;
        for (int bb = 0; bb < BB; ++bb) {
            float lb = 1.0f - bsum[bb] * (1.0f / (float)HW);
            if (bfg[bb]) loss += lb;
        }
        loss *= (1.0f / (float)BB);
        if (isnan(loss)) loss = 0.0f;
        else if (isinf(loss)) loss = (loss > 0.0f) ? 1.0f : 0.0f;
        out[0] = loss;
    }
}

extern "C" void kernel_launch(void* const* d_in, const int* in_sizes, int n_in,
                              void* d_out, int out_size, void* d_ws, size_t ws_size,
                              hipStream_t stream) {
    (void)in_sizes; (void)n_in; (void)out_size; (void)ws_size;
    const float* pred = (const float*)d_in[0];   // [4,3,256,256] f32
    const int*   lab  = (const int*)d_in[1];     // [4,256,256] i32

    char* wsb = (char*)d_ws;
    float* dbuf = (float*)wsb;                                    // 24*65536 f32 = 6 MB
    size_t off  = (size_t)NM * HW * sizeof(float);
    int*   bmax = (int*)(wsb + off);              off += 256;     // 24 slots + pad
    float* psum = (float*)(wsb + off);            off += 1024 * sizeof(float);
    int*   pfg  = (int*)  (wsb + off);            off += 1024 * sizeof(int);
    unsigned char* codes = (unsigned char*)(wsb + off);           // 256 KB
    off += (size_t)BB * HW;
    off = (off + 255) & ~(size_t)255;
    unsigned long long* bits = (unsigned long long*)(wsb + off);  // 192 KB

    // Proven 4-launch topology; every scratch word (incl. bmax atomic slots,
    // zeroed in rowpass) is written before it is read --- no memset needed.
    k_rowpass <<<NBLK,    256, 0, stream>>>(pred, lab, bits, codes, bmax);
    k_colpass <<<NM * 32, 256, 0, stream>>>(bits, dbuf, bmax);
    k_final   <<<NBLK,    256, 0, stream>>>(codes, dbuf, bmax, psum, pfg);
    k_finalize<<<1,       256, 0, stream>>>(psum, pfg, (float*)d_out);
}

// Round 7
// 74.004 us; speedup vs baseline: 1.2901x; 1.2901x over previous
//
#include <hip/hip_runtime.h>

// Problem constants
#define HH 256
#define WW 256
#define BB 4
#define CC 3
#define HW 65536          // H*W
#define NM 24             // 2*B*C masks (0..11 lab, 12..23 pred)
#define NBLK 1024
#define BIGF 1e9f
#define LIMITF 331776.0f  // 576*576
#define EPSF 1e-5f

// Ledger (dur_us): R0 4-launch 80.8 | R2 fused 90.6 | R3 2-launch 85.0 |
// R4 3-launch 84.1 | R5 4-launch + bitmap d1 74.7 | R6 +atomicMax bmax 95.5.
// R6 lesson: 768 device-scope atomicMax ops onto ONE 128B line (24 slots)
// serialize at the coherent point -> worse than the LDS reduction + 768
// plain stores they replaced (Guideline 12: pre-reduce, and spread atomic
// targets across lines -- a single shared line is the pathological case).
// R16: strict revert to the proven R5 source (disambiguation run).
// Structure: 41us harness fill + ~10us fixed graph overhead + ~23us for 4
// latency-bound kernels (traffic ~16MB = 2.5us at HBM; 10x below runtime);
// all tested sync alternatives (1/2/3-launch, coherent path, in-kernel
// waits, atomic reduction) measured worse than plain kernel boundaries.

// ---------------------------------------------------------------------------
// Pass 1: per-(batch,row) zero-pixel bitmaps for all 6 masks + per-pixel
// code byte (lab | argmax<<2). grid: 4*256 blocks, 256 threads (col).
// bits layout: [m][row][4] u64 --- bit k of word w = column w*64+k.
// ---------------------------------------------------------------------------
__global__ __launch_bounds__(256) void k_rowpass(const float* __restrict__ pred,
                                                 const int* __restrict__ lab,
                                                 unsigned long long* __restrict__ bits,
                                                 unsigned char* __restrict__ codes) {
    int blk = blockIdx.x;
    int b = blk >> 8;
    int i = blk & 255;
    int j = threadIdx.x;

    int lv = lab[(b << 16) + (i << 8) + j];
    const float* pb = pred + (((size_t)(b * 3)) << 16) + (i << 8) + j;
    float p0 = pb[0];
    float p1 = pb[(size_t)1 << 16];
    float p2 = pb[(size_t)2 << 16];
    int am = 0; float v = p0;
    if (p1 > v) { am = 1; v = p1; }
    if (p2 > v) { am = 2; }

    codes[(b << 16) + (i << 8) + j] = (unsigned char)(lv | (am << 2));

    __shared__ unsigned long long zm[6][4];
    int w = threadIdx.x >> 6;
    #pragma unroll
    for (int c = 0; c < 3; ++c) {
        unsigned long long zl = __ballot(lv != c);
        unsigned long long zp = __ballot(am != c);
        if ((threadIdx.x & 63) == 0) { zm[c][w] = zl; zm[3 + c][w] = zp; }
    }
    __syncthreads();

    // 24 u64 stores: thread t -> mask t>>2, word t&3 (32B contiguous/mask).
    if (threadIdx.x < 24) {
        int t = threadIdx.x >> 2;
        int w2 = threadIdx.x & 3;
        int c = (t < 3) ? t : (t - 3);
        int m = ((t < 3) ? 0 : 12) + b * 3 + c;
        bits[(((size_t)m) << 10) + (i << 2) + w2] = zm[t][w2];
    }
}

// ---------------------------------------------------------------------------
// Pass 2: recompute d1 from the mask bitmap (8KB in LDS), then column
// min-plus d[i,j]=min_k d1[k,j]+(i-k)^2 with the proven wave-uniform exact
// window (fast path Rmax<=32: guards make dk^2 a wave-scalar add,
// bit-identical; slow path: clamped, exact). One block owns 8 FULL columns.
// grid: 24*32 blocks, 256 threads. Writes final distances to dbuf + blkmax.
// ---------------------------------------------------------------------------
__global__ __launch_bounds__(256) void k_colpass(const unsigned long long* __restrict__ bits,
                                                 float* __restrict__ dbuf,
                                                 float* __restrict__ blkmax) {
    int blk = blockIdx.x;
    int m = blk >> 5;
    int j0 = (blk & 31) << 3;
    __shared__ float tile[320 * 9];            // rows 0..319 = k -32..287, stride 9
    __shared__ unsigned long long zb[256][4];  // row bitmaps, 8 KB
    float* base = dbuf + (((size_t)m) << 16);

    {   // stage bitmaps (1024 u64, 4/thread, coalesced) + guard rows = BIG
        const unsigned long long* bm = bits + (((size_t)m) << 10);
        int t = threadIdx.x;
        #pragma unroll
        for (int k = 0; k < 4; ++k) {
            int idx = t + (k << 8);
            zb[idx >> 2][idx & 3] = bm[idx];
        }
        int gr = t >> 3, gc = t & 7;
        tile[gr * 9 + gc] = BIGF;              // k = -32..-1
        tile[(288 + gr) * 9 + gc] = BIGF;      // k = 256..287
    }
    __syncthreads();

    int jj = threadIdx.x & 7;
    int ib = threadIdx.x >> 3;   // 0..31
    int j = j0 + jj;             // this thread's column

    // d1 for own 8 rows from the bitmap --- EXACT rowpass logic, relocated.
    #pragma unroll
    for (int r = 0; r < 8; ++r) {
        int row = ib + (r << 5);
        int bestd = 512;  // sentinel > any possible distance (<=255)
        #pragma unroll
        for (int w2 = 0; w2 < 4; ++w2) {
            unsigned long long z = zb[row][w2];
            int basew = w2 << 6;
            int rel = j - basew;
            unsigned long long mle;   // bits at positions <= rel
            if (rel >= 63)      mle = ~0ULL;
            else if (rel < 0)   mle = 0ULL;
            else                mle = (2ULL << rel) - 1ULL;
            unsigned long long zlo = z & mle;
            if (zlo) {
                int p = basew + 63 - __clzll(zlo);
                int d = j - p;
                if (d < bestd) bestd = d;
            }
            unsigned long long zr = z & ~mle;
            if (zr) {
                int p = basew + __ffsll(zr) - 1;
                int d = p - j;
                if (d < bestd) bestd = d;
            }
        }
        tile[(row + 32) * 9 + jj] = (bestd >= 512) ? BIGF : (float)(bestd * bestd);
    }
    __syncthreads();

    float acc[8];
    float dmax = 0.0f;
    #pragma unroll
    for (int r = 0; r < 8; ++r) {
        acc[r] = tile[(ib + (r << 5) + 32) * 9 + jj];   // k=i candidate
        dmax = fmaxf(dmax, acc[r]);
    }
    #pragma unroll
    for (int off = 32; off; off >>= 1)
        dmax = fmaxf(dmax, __shfl_xor(dmax, off, 64));
    int Rmax = (int)sqrtf(dmax) + 1;
    if (Rmax > 255) Rmax = 255;

    if (Rmax <= 32) {
        // Fast path: guards cover k=i+o fully; dk^2 = o^2 wave-scalar.
        for (int o = -Rmax; o <= Rmax; ++o) {
            float o2 = (float)(o * o);
            #pragma unroll
            for (int r = 0; r < 8; ++r)
                acc[r] = fminf(acc[r], o2 + tile[(ib + (r << 5) + 32 + o) * 9 + jj]);
        }
    } else {
        // Slow path (BIG rows in wave): clamped candidates, exact full logic.
        for (int o = -Rmax; o <= Rmax; ++o) {
            #pragma unroll
            for (int r = 0; r < 8; ++r) {
                int i = ib + (r << 5);
                int k = i + o;
                k = (k < 0) ? 0 : ((k > 255) ? 255 : k);
                float dk = (float)(k - i);
                acc[r] = fminf(acc[r], fmaf(dk, dk, tile[(k + 32) * 9 + jj]));
            }
        }
    }

    float lmax = 0.0f;
    #pragma unroll
    for (int r = 0; r < 8; ++r) {
        int i = ib + (r << 5);
        base[(i << 8) + j0 + jj] = acc[r];
        lmax = fmaxf(lmax, acc[r]);
    }

    #pragma unroll
    for (int off = 32; off; off >>= 1)
        lmax = fmaxf(lmax, __shfl_down(lmax, off, 64));
    __shared__ float wmax[4];
    if ((threadIdx.x & 63) == 0) wmax[threadIdx.x >> 6] = lmax;
    __syncthreads();
    if (threadIdx.x == 0)
        blkmax[blk] = fmaxf(fmaxf(wmax[0], wmax[1]), fmaxf(wmax[2], wmax[3]));
}

// ---------------------------------------------------------------------------
// Pass 3: per-pixel cosine sim -> per-BLOCK partials (byte-identical to R0).
// grid: 1024 blocks x 256 (blocks 256b..256b+255 cover batch b).
// ---------------------------------------------------------------------------
__global__ __launch_bounds__(256) void k_final(const unsigned char* __restrict__ codes,
                                               const float* __restrict__ dbuf,
                                               const float* __restrict__ blkmax,
                                               float* __restrict__ psum,
                                               int* __restrict__ pfg) {
    __shared__ float inv[NM];
    if (threadIdx.x < NM) {
        const float* bm = blkmax + (threadIdx.x << 5);
        float v = 0.0f;
        #pragma unroll
        for (int s = 0; s < 32; ++s) v = fmaxf(v, bm[s]);
        inv[threadIdx.x] = 1.0f / (fminf(sqrtf(v), LIMITF) + EPSF);
    }
    __syncthreads();

    int b = blockIdx.x >> 8;                         // uniform per block
    int pix = ((blockIdx.x & 255) << 8) + threadIdx.x;

    int code = codes[(b << 16) + pix];
    int lv = code & 3;
    int am = code >> 2;

    float slab = 0.0f, spred = 0.0f;
    #pragma unroll
    for (int c = 0; c < 3; ++c) {
        int ml = b * 3 + c;
        float dl = dbuf[(((size_t)ml) << 16) + pix];
        slab += sqrtf(dl) * inv[ml];
        float dp = dbuf[(((size_t)(ml + 12)) << 16) + pix];
        spred += sqrtf(dp) * inv[ml + 12];
    }

    float dot = spred * slab + ((am == lv) ? 1.0f : 0.0f);
    float na = sqrtf(spred * spred + 1.0f);
    float nb = sqrtf(slab * slab + 1.0f);
    float sim = dot / (fmaxf(na, 1e-8f) * fmaxf(nb, 1e-8f));

    unsigned long long fg = __ballot(lv > 0);

    #pragma unroll
    for (int off = 32; off; off >>= 1)
        sim += __shfl_down(sim, off, 64);
    __shared__ float wsum[4];
    __shared__ int wfg[4];
    if ((threadIdx.x & 63) == 0) {
        wsum[threadIdx.x >> 6] = sim;
        wfg[threadIdx.x >> 6] = (fg != 0ULL) ? 1 : 0;
    }
    __syncthreads();
    if (threadIdx.x == 0) {
        psum[blockIdx.x] = wsum[0] + wsum[1] + wsum[2] + wsum[3];
        pfg[blockIdx.x] = wfg[0] | wfg[1] | wfg[2] | wfg[3];
    }
}

// ---------------------------------------------------------------------------
// Reduce 1024 block partials -> loss (byte-identical to R0).
// ---------------------------------------------------------------------------
__global__ __launch_bounds__(256) void k_finalize(const float* __restrict__ psum,
                                                  const int* __restrict__ pfg,
                                                  float* __restrict__ out) {
    int t = threadIdx.x;
    int b = t >> 6, l = t & 63;
    int base = (b << 8) + l;
    float s = psum[base] + psum[base + 64] + psum[base + 128] + psum[base + 192];
    int f = pfg[base] | pfg[base + 64] | pfg[base + 128] | pfg[base + 192];
    #pragma unroll
    for (int off = 32; off; off >>= 1) {
        s += __shfl_down(s, off, 64);
        f |= __shfl_down(f, off, 64);
    }
    __shared__ float bsum[4];
    __shared__ int bfg[4];
    if (l == 0) { bsum[b] = s; bfg[b] = f; }
    __syncthreads();
    if (t == 0) {
        float loss = 0.0f;
        for (int bb = 0; bb < BB; ++bb) {
            float lb = 1.0f - bsum[bb] * (1.0f / (float)HW);
            if (bfg[bb]) loss += lb;
        }
        loss *= (1.0f / (float)BB);
        if (isnan(loss)) loss = 0.0f;
        else if (isinf(loss)) loss = (loss > 0.0f) ? 1.0f : 0.0f;
        out[0] = loss;
    }
}

extern "C" void kernel_launch(void* const* d_in, const int* in_sizes, int n_in,
                              void* d_out, int out_size, void* d_ws, size_t ws_size,
                              hipStream_t stream) {
    (void)in_sizes; (void)n_in; (void)out_size; (void)ws_size;
    const float* pred = (const float*)d_in[0];   // [4,3,256,256] f32
    const int*   lab  = (const int*)d_in[1];     // [4,256,256] i32

    char* wsb = (char*)d_ws;
    float* dbuf   = (float*)wsb;                                  // 24*65536 f32 = 6 MB
    size_t off    = (size_t)NM * HW * sizeof(float);
    float* blkmax = (float*)(wsb + off);          off += 768 * sizeof(float);
    float* psum   = (float*)(wsb + off);          off += 1024 * sizeof(float);
    int*   pfg    = (int*)  (wsb + off);          off += 1024 * sizeof(int);
    unsigned char* codes = (unsigned char*)(wsb + off);           // 256 KB
    off += (size_t)BB * HW;
    off = (off + 255) & ~(size_t)255;
    unsigned long long* bits = (unsigned long long*)(wsb + off);  // 192 KB

    // Proven 4-launch topology (best measured sync structure); every scratch
    // word is written before it is read --- no memset needed.
    k_rowpass <<<NBLK,    256, 0, stream>>>(pred, lab, bits, codes);
    k_colpass <<<NM * 32, 256, 0, stream>>>(bits, dbuf, blkmax);
    k_final   <<<NBLK,    256, 0, stream>>>(codes, dbuf, blkmax, psum, pfg);
    k_finalize<<<1,       256, 0, stream>>>(psum, pfg, (float*)d_out);
}